// Round 11
// baseline (288.497 us; speedup 1.0000x reference)
//
#include <hip/hip_runtime.h>
#include <hip/hip_bf16.h>

// HamGraphConvolution: N=100k nodes, D=64 feats, H=4 heads (DK=16), E=1.6M edges.
// xt = c1*x + c2*(x@W^T)  (Hamiltonian 4-step linear recurrence folded on host)
// GAT-style attention normalized over col, aggregated over row.
// Softmax max-subtraction skipped: shift-invariant, eps 1e-16 unreachable.
// R11: xt stored bf16 (halves gather traffic), scores fp32.
// R12 FAILED (block-per-bucket fused aggr): collapsed TLP. Reverted.
// R13/R15: k_aggr 8 groups x 8 lanes, 16B/lane, 32 edges in flight: 53->47us
//     (R14 FAILED: rows-serial-per-wave starved latency hiding).
// R16: k_node MFMA GEMM (no LDS), scores folded as geff B-cols: 308->301.
// R17 FAILED (global-atomic denom, 333us): fp32 atomicAdd write-through to
//     HBM (32B/atomic). NEVER hot-accumulate via scattered global atomics.
// R18/R19 FAILED (smaller buckets/EC): scatter write amplification 8x.
//     Scatter locality wants few buckets & big EC; TLP wants many blocks.
// R20: split-K denom (4 blocks/bucket, coalesced partials + k_comb): ->289.
// R21: k_front fuses geff+node+hist (partitioned grid); scatter inlines the
//     Btot scan (k_base2 deleted): ->281.
// R22: (a) hist granularity decoupled from scatter: EC_H=2048 (782 hist
//     blocks, 2x TLP) while scatter keeps EC=4096 (write locality); scatter
//     reads scanned H at column 2*blk. (b) sort2 split: count role fused
//     with denom_p in k_mid (independent, complementary resources overlap);
//     k_place rebuilds cursors from rowptr after k_comb.

#define LRELU(v) ((v) > 0.0f ? (v) : 0.2f * (v))

#define EC 4096      // edges per scatter block
#define ECH 2048     // edges per hist block (2x TLP for the LDS-atomic role)
#define BSC 256      // col-bucket size (shift 8)
#define BSR 128      // row-bucket size (shift 7)
#define DS 4         // denom split factor (blocks per col-bucket)
#define SLOTS 4      // unrolled edge slots in k_aggr (8 edges each)

typedef __attribute__((ext_vector_type(8))) short bf16x8;
typedef __attribute__((ext_vector_type(4))) float f32x4;

__device__ __forceinline__ float bf16_to_f32(unsigned short u) {
    return __uint_as_float((unsigned int)u << 16);
}
__device__ __forceinline__ float bflo(unsigned int u) {
    return __uint_as_float(u << 16);
}
__device__ __forceinline__ float bfhi(unsigned int u) {
    return __uint_as_float(u & 0xFFFF0000u);
}
__device__ __forceinline__ unsigned short f32_to_bf16(float f) {
    __hip_bfloat16 h = __float2bfloat16(f);  // RTN
    return *reinterpret_cast<unsigned short*>(&h);
}

// R21/R22 fused front: blocks [0,nbn) = node role (geff in LDS + R16 MFMA
// node GEMM); blocks [nbn, nbn+nblkH) = hist role at ECH granularity.
__global__ __launch_bounds__(256) void k_front(const float* __restrict__ x,
                                               const float* __restrict__ W,
                                               const float* __restrict__ a,
                                               const int* __restrict__ row,
                                               const int* __restrict__ col,
                                               unsigned short* __restrict__ xt16,
                                               float* __restrict__ s_src,
                                               float* __restrict__ s_dst,
                                               int* __restrict__ Hr,
                                               int* __restrict__ Hc,
                                               int n, int e, int nbn, int nblkH,
                                               int nbr, int nbc,
                                               float c1, float c2) {
    __shared__ unsigned short geffL[16 * 64];  // 2KB
    __shared__ int hr[1024];
    __shared__ int hc[512];
    int t = threadIdx.x;
    if (blockIdx.x < nbn) {
        // ---- geff[h][k] into LDS. cols 0-3 src-hi, 4-7 dst-hi, 8-11 src-lo,
        // 12-15 dst-lo.
        {
            int k = t & 63, h = t >> 6;
            float ssrc = 0.0f, sdst = 0.0f;
#pragma unroll
            for (int d = 0; d < 16; ++d) {
                float w = W[(h * 16 + d) * 64 + k];
                ssrc += w * a[d];
                sdst += w * a[16 + d];
            }
            float gsrc = c2 * ssrc, gdst = c2 * sdst;
            if ((k >> 4) == h) {
                gsrc += c1 * a[k & 15];
                gdst += c1 * a[16 + (k & 15)];
            }
            unsigned short sh = f32_to_bf16(gsrc);
            unsigned short sl = f32_to_bf16(gsrc - bf16_to_f32(sh));
            unsigned short dh = f32_to_bf16(gdst);
            unsigned short dl = f32_to_bf16(gdst - bf16_to_f32(dh));
            geffL[h * 64 + k] = sh;
            geffL[(4 + h) * 64 + k] = dh;
            geffL[(8 + h) * 64 + k] = sl;
            geffL[(12 + h) * 64 + k] = dl;
        }
        __syncthreads();

        // ---- R16 MFMA node body. C-layout (m89): col=lane&15,
        // row=(lane>>4)*4+reg.
        int wave = t >> 6;
        int lane = t & 63;
        int nb = blockIdx.x * 64 + wave * 16;
        if (nb >= n) return;
        int colg = lane & 15;
        int grp = lane >> 4;
        int k0 = grp << 3;

        bf16x8 wf[4][2];
#pragma unroll
        for (int ct = 0; ct < 4; ++ct) {
#pragma unroll
            for (int ks = 0; ks < 2; ++ks) {
                const float* wr = W + (size_t)(ct * 16 + colg) * 64 + k0 + ks * 32;
                float4 w0 = *(const float4*)(wr);
                float4 w1 = *(const float4*)(wr + 4);
                bf16x8 f;
                f[0] = (short)f32_to_bf16(w0.x); f[1] = (short)f32_to_bf16(w0.y);
                f[2] = (short)f32_to_bf16(w0.z); f[3] = (short)f32_to_bf16(w0.w);
                f[4] = (short)f32_to_bf16(w1.x); f[5] = (short)f32_to_bf16(w1.y);
                f[6] = (short)f32_to_bf16(w1.z); f[7] = (short)f32_to_bf16(w1.w);
                wf[ct][ks] = f;
            }
        }
        bf16x8 gf[2];
#pragma unroll
        for (int ks = 0; ks < 2; ++ks)
            gf[ks] = *(const bf16x8*)(geffL + colg * 64 + k0 + ks * 32);

        int arow = nb + colg;
        if (arow >= n) arow = n - 1;
        const float* xr = x + (size_t)arow * 64 + k0;
        bf16x8 af[2];
#pragma unroll
        for (int ks = 0; ks < 2; ++ks) {
            float4 x0 = *(const float4*)(xr + ks * 32);
            float4 x1 = *(const float4*)(xr + ks * 32 + 4);
            bf16x8 f;
            f[0] = (short)f32_to_bf16(x0.x); f[1] = (short)f32_to_bf16(x0.y);
            f[2] = (short)f32_to_bf16(x0.z); f[3] = (short)f32_to_bf16(x0.w);
            f[4] = (short)f32_to_bf16(x1.x); f[5] = (short)f32_to_bf16(x1.y);
            f[6] = (short)f32_to_bf16(x1.z); f[7] = (short)f32_to_bf16(x1.w);
            af[ks] = f;
        }

        f32x4 acc[5];
#pragma unroll
        for (int i = 0; i < 5; ++i) acc[i] = (f32x4){0.f, 0.f, 0.f, 0.f};
#pragma unroll
        for (int ct = 0; ct < 4; ++ct) {
            acc[ct] = __builtin_amdgcn_mfma_f32_16x16x32_bf16(af[0], wf[ct][0], acc[ct], 0, 0, 0);
            acc[ct] = __builtin_amdgcn_mfma_f32_16x16x32_bf16(af[1], wf[ct][1], acc[ct], 0, 0, 0);
        }
        acc[4] = __builtin_amdgcn_mfma_f32_16x16x32_bf16(af[0], gf[0], acc[4], 0, 0, 0);
        acc[4] = __builtin_amdgcn_mfma_f32_16x16x32_bf16(af[1], gf[1], acc[4], 0, 0, 0);

#pragma unroll
        for (int ct = 0; ct < 4; ++ct) {
            int c = ct * 16 + colg;
#pragma unroll
            for (int rr = 0; rr < 4; ++rr) {
                int node = nb + grp * 4 + rr;
                if (node < n) {
                    float xv = x[(size_t)node * 64 + c];
                    float xtv = c1 * xv + c2 * acc[ct][rr];
                    xt16[(size_t)node * 64 + c] = f32_to_bf16(xtv);
                }
            }
        }
#pragma unroll
        for (int rr = 0; rr < 4; ++rr) {
            float v = acc[4][rr];
            float tot = v + __shfl_xor(v, 8, 64);
            int node = nb + grp * 4 + rr;
            if (node < n) {
                if (colg < 4) s_src[node * 4 + colg] = tot;
                else if (colg < 8) s_dst[node * 4 + (colg - 4)] = tot;
            }
        }
    } else {
        // ---- hist role at ECH granularity: H layout [bucket][histblock]
        int blk = blockIdx.x - nbn;
        for (int i = t; i < 1024; i += 256) hr[i] = 0;
        for (int i = t; i < 512; i += 256) hc[i] = 0;
        __syncthreads();
        int base = blk * ECH;
#pragma unroll
        for (int j = 0; j < ECH / 256; ++j) {
            int i = base + t + j * 256;
            if (i < e) {
                atomicAdd(&hr[row[i] >> 7], 1);
                atomicAdd(&hc[col[i] >> 8], 1);
            }
        }
        __syncthreads();
        for (int b = t; b < nbr; b += 256) Hr[(size_t)b * nblkH + blk] = hr[b];
        for (int b = t; b < nbc; b += 256) Hc[(size_t)b * nblkH + blk] = hc[b];
    }
}

// fused: exclusive scan of Hr rows (blocks [0,nbr)) and Hc rows (blocks
// [nbr, nbr+nbc)); per-bucket totals to BtotR/BtotC. nblkH<=1024 (4 vals/thr).
__global__ __launch_bounds__(256) void k_scanH2(int* __restrict__ Hr,
                                                int* __restrict__ Hc,
                                                int* __restrict__ BtotR,
                                                int* __restrict__ BtotC,
                                                int nblkH, int nbr) {
    __shared__ int vals[1024];
    __shared__ int part[256];
    int t = threadIdx.x;
    int bb = blockIdx.x;
    int* Hb;
    int* Btot;
    if (bb < nbr) {
        Hb = Hr + (size_t)bb * nblkH;
        Btot = BtotR + bb;
    } else {
        Hb = Hc + (size_t)(bb - nbr) * nblkH;
        Btot = BtotC + (bb - nbr);
    }
    for (int i = t; i < nblkH; i += 256) vals[i] = Hb[i];
    __syncthreads();
    int c0 = t * 4;
    int s = 0;
#pragma unroll
    for (int j = 0; j < 4; ++j)
        if (c0 + j < nblkH) s += vals[c0 + j];
    part[t] = s;
    __syncthreads();
    for (int d = 1; d < 256; d <<= 1) {
        int add = (t >= d) ? part[t - d] : 0;
        __syncthreads();
        part[t] += add;
        __syncthreads();
    }
    int run = part[t] - s;
#pragma unroll
    for (int j = 0; j < 4; ++j) {
        int i = c0 + j;
        if (i < nblkH) {
            int v = vals[i];
            Hb[i] = run;
            run += v;
        }
    }
    if (t == 255) *Btot = part[255];
}

// R21 scatter with inline base scan; R22: reads scanned H at column 2*blk
// (EC = 2*ECH). Block 0 publishes BbR/BbC. Plain stores, no global atomics.
__global__ __launch_bounds__(256) void k_scatter_dual(
    const int* __restrict__ row, const int* __restrict__ col,
    const int* __restrict__ Hr, const int* __restrict__ Hc,
    const int* __restrict__ BtotR, const int* __restrict__ BtotC,
    int* __restrict__ BbR, int* __restrict__ BbC,
    int* __restrict__ ebr, int* __restrict__ ebc,
    int e, int nblkH, int nbr, int nbc) {
    __shared__ int vals[1024];
    __shared__ int part[256];
    __shared__ int curr[1024];
    __shared__ int curc[512];
    int t = threadIdx.x;
    int blk = blockIdx.x;
    int hcol = blk << 1;  // this block's first H column
    // ---- scan BtotR -> curr = base + Hr[.][hcol]; block 0 -> BbR
    for (int i = t; i < nbr; i += 256) vals[i] = BtotR[i];
    __syncthreads();
    {
        int c0 = t * 4, s = 0;
#pragma unroll
        for (int j = 0; j < 4; ++j)
            if (c0 + j < nbr) s += vals[c0 + j];
        part[t] = s;
        __syncthreads();
        for (int d = 1; d < 256; d <<= 1) {
            int add = (t >= d) ? part[t - d] : 0;
            __syncthreads();
            part[t] += add;
            __syncthreads();
        }
        int run = part[t] - s;
#pragma unroll
        for (int j = 0; j < 4; ++j) {
            int i = c0 + j;
            if (i < nbr) {
                int v = vals[i];
                curr[i] = run + Hr[(size_t)i * nblkH + hcol];
                if (blk == 0) BbR[i] = run;
                run += v;
            }
        }
        if (blk == 0 && t == 255) BbR[nbr] = part[255];
    }
    __syncthreads();
    // ---- scan BtotC -> curc; block 0 -> BbC
    for (int i = t; i < nbc; i += 256) vals[i] = BtotC[i];
    __syncthreads();
    {
        int c0 = t * 4, s = 0;
#pragma unroll
        for (int j = 0; j < 4; ++j)
            if (c0 + j < nbc) s += vals[c0 + j];
        part[t] = s;
        __syncthreads();
        for (int d = 1; d < 256; d <<= 1) {
            int add = (t >= d) ? part[t - d] : 0;
            __syncthreads();
            part[t] += add;
            __syncthreads();
        }
        int run = part[t] - s;
#pragma unroll
        for (int j = 0; j < 4; ++j) {
            int i = c0 + j;
            if (i < nbc) {
                int v = vals[i];
                curc[i] = run + Hc[(size_t)i * nblkH + hcol];
                if (blk == 0) BbC[i] = run;
                run += v;
            }
        }
        if (blk == 0 && t == 255) BbC[nbc] = part[255];
    }
    __syncthreads();
    // ---- dual scatter: ebr payload c<<7|r_low, ebc payload r<<8|c_low
    int base = blk * EC;
#pragma unroll
    for (int j = 0; j < EC / 256; ++j) {
        int i = base + t + j * 256;
        if (i < e) {
            int r = row[i], c = col[i];
            int pr = atomicAdd(&curr[r >> 7], 1);
            ebr[pr] = (c << 7) | (r & 127);
            int pc = atomicAdd(&curc[c >> 8], 1);
            ebc[pc] = (r << 8) | (c & 255);
        }
    }
}

// R22 fused mid: blocks [0,ndenom) = R20 split-K denom slices (LDS acc,
// coalesced partials); blocks [ndenom, ndenom+nbr) = sort2 counting role
// (rowptr from per-row-bucket histogram). Independent workloads overlap.
__global__ __launch_bounds__(256) void k_mid(const int* __restrict__ ebc,
                                             const int* __restrict__ BbC,
                                             const int* __restrict__ ebr,
                                             const int* __restrict__ BbR,
                                             const float* __restrict__ s_src,
                                             const float* __restrict__ s_dst,
                                             float* __restrict__ part,
                                             int* __restrict__ rowptr,
                                             int n, int n4, int e, int ndenom) {
    __shared__ float acc[BSC * 4];
    __shared__ float sd[BSC * 4];
    __shared__ int cnt[BSR];
    __shared__ int pfx[BSR];
    int t = threadIdx.x;
    if (blockIdx.x < ndenom) {
        int bucket = blockIdx.x >> 2;
        int slice = blockIdx.x & 3;
        int cbase = bucket << 8;
        for (int i = t; i < BSC * 4; i += 256) {
            acc[i] = 0.0f;
            int c4 = cbase * 4 + i;
            sd[i] = (c4 < n4) ? s_dst[c4] : 0.0f;
        }
        __syncthreads();
        int start = BbC[bucket], end = BbC[bucket + 1];
        int len = end - start;
        int i0 = start + (int)(((long long)len * slice) >> 2);
        int i1 = start + (int)(((long long)len * (slice + 1)) >> 2);
        for (int i = i0 + t; i < i1; i += 256) {
            int p = ebc[i];
            int r = p >> 8, cl = p & 255;
            float4 ss = *(const float4*)(s_src + (size_t)r * 4);
            atomicAdd(&acc[cl * 4 + 0], __expf(LRELU(ss.x + sd[cl * 4 + 0])));
            atomicAdd(&acc[cl * 4 + 1], __expf(LRELU(ss.y + sd[cl * 4 + 1])));
            atomicAdd(&acc[cl * 4 + 2], __expf(LRELU(ss.z + sd[cl * 4 + 2])));
            atomicAdd(&acc[cl * 4 + 3], __expf(LRELU(ss.w + sd[cl * 4 + 3])));
        }
        __syncthreads();
        float* ps = part + (size_t)slice * n4;
        for (int i = t; i < BSC * 4; i += 256) {
            int c4 = cbase * 4 + i;
            if (c4 < n4) ps[c4] = acc[i];
        }
    } else {
        // ---- sort2 count role: per-row exclusive positions -> rowptr
        int b = blockIdx.x - ndenom;
        int rbase = b << 7;
        if (t < BSR) cnt[t] = 0;
        __syncthreads();
        int start = BbR[b], end = BbR[b + 1];
        for (int i = start + t; i < end; i += 256)
            atomicAdd(&cnt[ebr[i] & 127], 1);
        __syncthreads();
        if (t < BSR) pfx[t] = cnt[t];
        __syncthreads();
        for (int d = 1; d < BSR; d <<= 1) {
            int v = (t < BSR && t >= d) ? pfx[t - d] : 0;
            __syncthreads();
            if (t < BSR) pfx[t] += v;
            __syncthreads();
        }
        if (t < BSR) {
            int r = rbase + t;
            if (r < n) rowptr[r] = start + pfx[t] - cnt[t];
        }
        if (b == 0 && t == 0) rowptr[n] = e;
    }
}

// combine DS partials -> sdr[c] = {s_dst[c][0..3], 1/den[c][0..3]} (32B)
__global__ __launch_bounds__(256) void k_comb(const float* __restrict__ part,
                                              const float* __restrict__ s_dst,
                                              float* __restrict__ sdr, int n4) {
    int idx = blockIdx.x * 256 + threadIdx.x;
    if (idx >= n4) return;
    float s = part[idx] + part[(size_t)n4 + idx] + part[(size_t)2 * n4 + idx] +
              part[(size_t)3 * n4 + idx];
    int c = idx >> 2, h = idx & 3;
    sdr[(size_t)c * 8 + h] = s_dst[idx];
    sdr[(size_t)c * 8 + 4 + h] = 1.0f / (s + 1e-16f);
}

// R22 place pass: cursors rebuilt from rowptr (exact exclusive positions),
// then permute ebr -> row-sorted int2{c<<6, w}; one 32B sdr gather per edge.
__global__ __launch_bounds__(256) void k_place(const int* __restrict__ ebr,
                                               const int* __restrict__ BbR,
                                               const float* __restrict__ s_src,
                                               const float* __restrict__ sdr,
                                               const int* __restrict__ rowptr,
                                               int2* __restrict__ cwp,
                                               int n, int e) {
    __shared__ int cur[BSR];
    __shared__ float ssh[BSR * 4];
    int t = threadIdx.x;
    int b = blockIdx.x;
    int rbase = b << 7;
    if (t < BSR) cur[t] = rowptr[min(rbase + t, n)];
    for (int i = t; i < BSR * 4; i += 256) {
        int g = rbase * 4 + i;
        ssh[i] = (g < n * 4) ? s_src[g] : 0.0f;
    }
    __syncthreads();
    int start = BbR[b], end = BbR[b + 1];
    for (int i = start + t; i < end; i += 256) {
        int p = ebr[i];
        int rl = p & 127, c = p >> 7;
        float4 sd = *(const float4*)(sdr + (size_t)c * 8);
        float4 rd = *(const float4*)(sdr + (size_t)c * 8 + 4);
        float wv = __expf(LRELU(ssh[rl * 4 + 0] + sd.x)) * rd.x +
                   __expf(LRELU(ssh[rl * 4 + 1] + sd.y)) * rd.y +
                   __expf(LRELU(ssh[rl * 4 + 2] + sd.z)) * rd.z +
                   __expf(LRELU(ssh[rl * 4 + 3] + sd.w)) * rd.w;
        int pos = atomicAdd(&cur[rl], 1);
        // c pre-shifted to element offset (c*64) for k_aggr's 32-bit addressing
        cwp[pos] = make_int2(c << 6, __float_as_int(0.25f * wv));
    }
}

// R15 wave-per-row CSR gather-reduce: 8 groups x 8 lanes, each group gathers a
// different edge's 128B row as uint4 (16B/lane = 8 bf16). SLOTS=4 unrolled ->
// up to 32 edges in flight; slots gated by k<nk (wave-uniform skip).
__global__ __launch_bounds__(256) void k_aggr(const int* __restrict__ rowptr,
                                              const int2* __restrict__ cwp,
                                              const unsigned short* __restrict__ xt16,
                                              float* __restrict__ out, int n, int e) {
    int r = blockIdx.x * 4 + (threadIdx.x >> 6);
    if (r >= n) return;
    int lane = threadIdx.x & 63;
    int g = lane >> 3;          // edge group 0..7
    unsigned le = (lane & 7) << 3;  // covers cols [le, le+8)
    int start = rowptr[r], end = rowptr[r + 1];
    float acc[8];
#pragma unroll
    for (int j = 0; j < 8; ++j) acc[j] = 0.0f;
    for (int base = start; base < end; base += SLOTS * 8) {
        int m = end - base;
        if (m > SLOTS * 8) m = SLOTS * 8;
        int nk = (m + 7) >> 3;  // slots needed (wave-uniform)
        uint4 u[SLOTS];
        float wv[SLOTS];
#pragma unroll
        for (int k = 0; k < SLOTS; ++k) {
            if (k < nk) {
                int idx = base + k * 8 + g;
                int idc = idx < e ? idx : e - 1;  // stay in-buffer
                int2 cw = cwp[idc];              // 8B meta, broadcast in group
                wv[k] = (idx < end) ? __int_as_float(cw.y) : 0.0f;
                u[k] = *(const uint4*)(xt16 + ((unsigned)cw.x + le));
            }
        }
#pragma unroll
        for (int k = 0; k < SLOTS; ++k) {
            if (k < nk) {
                acc[0] = fmaf(wv[k], bflo(u[k].x), acc[0]);
                acc[1] = fmaf(wv[k], bfhi(u[k].x), acc[1]);
                acc[2] = fmaf(wv[k], bflo(u[k].y), acc[2]);
                acc[3] = fmaf(wv[k], bfhi(u[k].y), acc[3]);
                acc[4] = fmaf(wv[k], bflo(u[k].z), acc[4]);
                acc[5] = fmaf(wv[k], bfhi(u[k].z), acc[5]);
                acc[6] = fmaf(wv[k], bflo(u[k].w), acc[6]);
                acc[7] = fmaf(wv[k], bfhi(u[k].w), acc[7]);
            }
        }
    }
#pragma unroll
    for (int off = 8; off <= 32; off <<= 1) {
#pragma unroll
        for (int j = 0; j < 8; ++j) acc[j] += __shfl_xor(acc[j], off, 64);
    }
    if (lane < 8) {
        float4 a0 = {acc[0], acc[1], acc[2], acc[3]};
        float4 a1 = {acc[4], acc[5], acc[6], acc[7]};
        *(float4*)(out + (size_t)r * 64 + le) = a0;
        *(float4*)(out + (size_t)r * 64 + le + 4) = a1;
    }
}

extern "C" void kernel_launch(void* const* d_in, const int* in_sizes, int n_in,
                              void* d_out, int out_size, void* d_ws, size_t ws_size,
                              hipStream_t stream) {
    const float* x = (const float*)d_in[0];
    const int* ei = (const int*)d_in[1];
    // d_in[2] = edge_weight: unused by the reference
    const float* W = (const float*)d_in[3];
    const float* a = (const float*)d_in[4];
    int n = in_sizes[0] / 64;
    int e = in_sizes[1] / 2;
    const int* row = ei;
    const int* col = ei + e;
    float* out = (float*)d_out;

    int nblk = (e + EC - 1) / EC;       // 391 scatter blocks
    int nblkH = (e + ECH - 1) / ECH;    // 782 hist blocks (<=1024 for scanH2)
    int nbr = (n + BSR - 1) / BSR;      // 782 (<=1024 for scatter scan)
    int nbc = (n + BSC - 1) / BSC;      // 391 (<=512)
    int nbn = (n + 63) / 64;            // 1563 node blocks in k_front
    int n4 = n * 4;
    int ndenom = nbc * DS;              // 1564 denom slices in k_mid

    size_t o = 0;
    auto take = [&](size_t cnt) {
        size_t p = o;
        o += (cnt + 3) & ~(size_t)3;
        return p;
    };
    int* wsi = (int*)d_ws;
    unsigned short* xt16 = (unsigned short*)(wsi + take((size_t)n * 32));  // n*64 bf16
    float* s_src = (float*)(wsi + take((size_t)n * 4));
    float* s_dst = (float*)(wsi + take((size_t)n * 4));
    float* sdr = (float*)(wsi + take((size_t)n * 8));  // merged {s_dst, 1/den}
    float* part = (float*)(wsi + take((size_t)n * 4 * DS));  // denom partials
    int* Hr = wsi + take((size_t)nbr * nblkH);
    int* Hc = wsi + take((size_t)nbc * nblkH);
    int* BtotR = wsi + take(nbr);
    int* BbR = wsi + take(nbr + 1);
    int* BtotC = wsi + take(nbc);
    int* BbC = wsi + take(nbc + 1);
    int* ebr = wsi + take(e);
    int* cwbuf = wsi + take((size_t)2 * e);  // first e ints double as ebc
    int* ebc = cwbuf;            // dead after k_mid; k_place overwrites as int2
    int2* cwp = (int2*)cwbuf;
    int* rowptr = wsi + take(n + 1);

    // Fold 4-step (q,p) <- (q+0.25p, p-0.25q): xt = aq*x + bq*(x@W^T)
    float aq = 1.f, bq = 0.f, ap = 0.f, bp = 1.f;
    for (int i = 0; i < 4; ++i) {
        float naq = aq + 0.25f * ap, nbq = bq + 0.25f * bp;
        float nap = ap - 0.25f * aq, nbp = bp - 0.25f * bq;
        aq = naq; bq = nbq; ap = nap; bp = nbp;
    }

    k_front<<<nbn + nblkH, 256, 0, stream>>>(x, W, a, row, col, xt16, s_src,
                                             s_dst, Hr, Hc, n, e, nbn, nblkH,
                                             nbr, nbc, aq, bq);
    k_scanH2<<<nbr + nbc, 256, 0, stream>>>(Hr, Hc, BtotR, BtotC, nblkH, nbr);
    k_scatter_dual<<<nblk, 256, 0, stream>>>(row, col, Hr, Hc, BtotR, BtotC,
                                             BbR, BbC, ebr, ebc, e, nblkH,
                                             nbr, nbc);
    k_mid<<<ndenom + nbr, 256, 0, stream>>>(ebc, BbC, ebr, BbR, s_src, s_dst,
                                            part, rowptr, n, n4, e, ndenom);
    k_comb<<<(n4 + 255) / 256, 256, 0, stream>>>(part, s_dst, sdr, n4);
    k_place<<<nbr, 256, 0, stream>>>(ebr, BbR, s_src, sdr, rowptr, cwp, n, e);
    k_aggr<<<(n + 3) / 4, 256, 0, stream>>>(rowptr, cwp, xt16, out, n, e);
}

// Round 12
// 279.995 us; speedup vs baseline: 1.0304x; 1.0304x over previous
//
#include <hip/hip_runtime.h>
#include <hip/hip_bf16.h>

// HamGraphConvolution: N=100k nodes, D=64 feats, H=4 heads (DK=16), E=1.6M edges.
// xt = c1*x + c2*(x@W^T)  (Hamiltonian 4-step linear recurrence folded on host)
// GAT-style attention normalized over col, aggregated over row.
// Softmax max-subtraction skipped: shift-invariant, eps 1e-16 unreachable.
// R11: xt stored bf16 (halves gather traffic), scores fp32.
// R12 FAILED (block-per-bucket fused aggr): collapsed TLP. Reverted.
// R13/R15: k_aggr 8 groups x 8 lanes, 16B/lane, 32 edges in flight: 53->47us.
// R16: k_node MFMA GEMM (no LDS), scores folded as geff B-cols: 308->301.
// R17 FAILED (global-atomic denom, 333us): fp32 atomicAdd write-through to
//     HBM (32B/atomic). NEVER hot-accumulate via scattered global atomics.
// R18/R19 FAILED (smaller buckets/EC): scatter write amplification 8x.
//     Scatter locality wants few buckets & big EC; TLP wants many blocks.
// R20: split-K denom (4 blocks/bucket, coalesced partials + k_comb): ->289.
// R21: k_front fuses geff+node+hist; scatter inlines Btot scan: ->281 (best).
// R22 FAILED (+7us, confounded): ECH=2048 hist split doubled hist-block fixed
//     overhead + scanH2 width (k_front 48.8us top); k_mid fusion unmeasured.
// R23: de-confound -- exact R21 geometry (hist EC=4096, 391 H columns),
//     keeping ONLY the k_mid (denom slices || sort-count role) + k_place
//     split from R22. Isolates the overlap gain against the 281.3 baseline.

#define LRELU(v) ((v) > 0.0f ? (v) : 0.2f * (v))

#define EC 4096      // edges per hist/scatter block
#define BSC 256      // col-bucket size (shift 8)
#define BSR 128      // row-bucket size (shift 7)
#define DS 4         // denom split factor (blocks per col-bucket)
#define SLOTS 4      // unrolled edge slots in k_aggr (8 edges each)

typedef __attribute__((ext_vector_type(8))) short bf16x8;
typedef __attribute__((ext_vector_type(4))) float f32x4;

__device__ __forceinline__ float bf16_to_f32(unsigned short u) {
    return __uint_as_float((unsigned int)u << 16);
}
__device__ __forceinline__ float bflo(unsigned int u) {
    return __uint_as_float(u << 16);
}
__device__ __forceinline__ float bfhi(unsigned int u) {
    return __uint_as_float(u & 0xFFFF0000u);
}
__device__ __forceinline__ unsigned short f32_to_bf16(float f) {
    __hip_bfloat16 h = __float2bfloat16(f);  // RTN
    return *reinterpret_cast<unsigned short*>(&h);
}

// R21 fused front: blocks [0,nbn) = node role (geff recomputed into LDS,
// then R16 MFMA node GEMM); blocks [nbn, nbn+nblk) = hist role (EC=4096).
// All blocks co-resident -> roles overlap.
__global__ __launch_bounds__(256) void k_front(const float* __restrict__ x,
                                               const float* __restrict__ W,
                                               const float* __restrict__ a,
                                               const int* __restrict__ row,
                                               const int* __restrict__ col,
                                               unsigned short* __restrict__ xt16,
                                               float* __restrict__ s_src,
                                               float* __restrict__ s_dst,
                                               int* __restrict__ Hr,
                                               int* __restrict__ Hc,
                                               int n, int e, int nbn, int nblk,
                                               int nbr, int nbc,
                                               float c1, float c2) {
    __shared__ unsigned short geffL[16 * 64];  // 2KB
    __shared__ int hr[1024];
    __shared__ int hc[512];
    int t = threadIdx.x;
    if (blockIdx.x < nbn) {
        // ---- geff[h][k] into LDS. cols 0-3 src-hi, 4-7 dst-hi, 8-11 src-lo,
        // 12-15 dst-lo.
        {
            int k = t & 63, h = t >> 6;
            float ssrc = 0.0f, sdst = 0.0f;
#pragma unroll
            for (int d = 0; d < 16; ++d) {
                float w = W[(h * 16 + d) * 64 + k];
                ssrc += w * a[d];
                sdst += w * a[16 + d];
            }
            float gsrc = c2 * ssrc, gdst = c2 * sdst;
            if ((k >> 4) == h) {
                gsrc += c1 * a[k & 15];
                gdst += c1 * a[16 + (k & 15)];
            }
            unsigned short sh = f32_to_bf16(gsrc);
            unsigned short sl = f32_to_bf16(gsrc - bf16_to_f32(sh));
            unsigned short dh = f32_to_bf16(gdst);
            unsigned short dl = f32_to_bf16(gdst - bf16_to_f32(dh));
            geffL[h * 64 + k] = sh;
            geffL[(4 + h) * 64 + k] = dh;
            geffL[(8 + h) * 64 + k] = sl;
            geffL[(12 + h) * 64 + k] = dl;
        }
        __syncthreads();

        // ---- R16 MFMA node body. C-layout (m89): col=lane&15,
        // row=(lane>>4)*4+reg.
        int wave = t >> 6;
        int lane = t & 63;
        int nb = blockIdx.x * 64 + wave * 16;
        if (nb >= n) return;
        int colg = lane & 15;
        int grp = lane >> 4;
        int k0 = grp << 3;

        bf16x8 wf[4][2];
#pragma unroll
        for (int ct = 0; ct < 4; ++ct) {
#pragma unroll
            for (int ks = 0; ks < 2; ++ks) {
                const float* wr = W + (size_t)(ct * 16 + colg) * 64 + k0 + ks * 32;
                float4 w0 = *(const float4*)(wr);
                float4 w1 = *(const float4*)(wr + 4);
                bf16x8 f;
                f[0] = (short)f32_to_bf16(w0.x); f[1] = (short)f32_to_bf16(w0.y);
                f[2] = (short)f32_to_bf16(w0.z); f[3] = (short)f32_to_bf16(w0.w);
                f[4] = (short)f32_to_bf16(w1.x); f[5] = (short)f32_to_bf16(w1.y);
                f[6] = (short)f32_to_bf16(w1.z); f[7] = (short)f32_to_bf16(w1.w);
                wf[ct][ks] = f;
            }
        }
        bf16x8 gf[2];
#pragma unroll
        for (int ks = 0; ks < 2; ++ks)
            gf[ks] = *(const bf16x8*)(geffL + colg * 64 + k0 + ks * 32);

        int arow = nb + colg;
        if (arow >= n) arow = n - 1;
        const float* xr = x + (size_t)arow * 64 + k0;
        bf16x8 af[2];
#pragma unroll
        for (int ks = 0; ks < 2; ++ks) {
            float4 x0 = *(const float4*)(xr + ks * 32);
            float4 x1 = *(const float4*)(xr + ks * 32 + 4);
            bf16x8 f;
            f[0] = (short)f32_to_bf16(x0.x); f[1] = (short)f32_to_bf16(x0.y);
            f[2] = (short)f32_to_bf16(x0.z); f[3] = (short)f32_to_bf16(x0.w);
            f[4] = (short)f32_to_bf16(x1.x); f[5] = (short)f32_to_bf16(x1.y);
            f[6] = (short)f32_to_bf16(x1.z); f[7] = (short)f32_to_bf16(x1.w);
            af[ks] = f;
        }

        f32x4 acc[5];
#pragma unroll
        for (int i = 0; i < 5; ++i) acc[i] = (f32x4){0.f, 0.f, 0.f, 0.f};
#pragma unroll
        for (int ct = 0; ct < 4; ++ct) {
            acc[ct] = __builtin_amdgcn_mfma_f32_16x16x32_bf16(af[0], wf[ct][0], acc[ct], 0, 0, 0);
            acc[ct] = __builtin_amdgcn_mfma_f32_16x16x32_bf16(af[1], wf[ct][1], acc[ct], 0, 0, 0);
        }
        acc[4] = __builtin_amdgcn_mfma_f32_16x16x32_bf16(af[0], gf[0], acc[4], 0, 0, 0);
        acc[4] = __builtin_amdgcn_mfma_f32_16x16x32_bf16(af[1], gf[1], acc[4], 0, 0, 0);

#pragma unroll
        for (int ct = 0; ct < 4; ++ct) {
            int c = ct * 16 + colg;
#pragma unroll
            for (int rr = 0; rr < 4; ++rr) {
                int node = nb + grp * 4 + rr;
                if (node < n) {
                    float xv = x[(size_t)node * 64 + c];
                    float xtv = c1 * xv + c2 * acc[ct][rr];
                    xt16[(size_t)node * 64 + c] = f32_to_bf16(xtv);
                }
            }
        }
#pragma unroll
        for (int rr = 0; rr < 4; ++rr) {
            float v = acc[4][rr];
            float tot = v + __shfl_xor(v, 8, 64);
            int node = nb + grp * 4 + rr;
            if (node < n) {
                if (colg < 4) s_src[node * 4 + colg] = tot;
                else if (colg < 8) s_dst[node * 4 + (colg - 4)] = tot;
            }
        }
    } else {
        // ---- hist role: H layout [bucket][block]
        int blk = blockIdx.x - nbn;
        for (int i = t; i < 1024; i += 256) hr[i] = 0;
        for (int i = t; i < 512; i += 256) hc[i] = 0;
        __syncthreads();
        int base = blk * EC;
#pragma unroll
        for (int j = 0; j < EC / 256; ++j) {
            int i = base + t + j * 256;
            if (i < e) {
                atomicAdd(&hr[row[i] >> 7], 1);
                atomicAdd(&hc[col[i] >> 8], 1);
            }
        }
        __syncthreads();
        for (int b = t; b < nbr; b += 256) Hr[(size_t)b * nblk + blk] = hr[b];
        for (int b = t; b < nbc; b += 256) Hc[(size_t)b * nblk + blk] = hc[b];
    }
}

// fused: exclusive scan of Hr rows (blocks [0,nbr)) and Hc rows (blocks
// [nbr, nbr+nbc)); per-bucket totals to BtotR/BtotC. nblk<=512.
__global__ __launch_bounds__(256) void k_scanH2(int* __restrict__ Hr,
                                                int* __restrict__ Hc,
                                                int* __restrict__ BtotR,
                                                int* __restrict__ BtotC,
                                                int nblk, int nbr) {
    __shared__ int vals[512];
    __shared__ int part[256];
    int t = threadIdx.x;
    int bb = blockIdx.x;
    int* Hb;
    int* Btot;
    if (bb < nbr) {
        Hb = Hr + (size_t)bb * nblk;
        Btot = BtotR + bb;
    } else {
        Hb = Hc + (size_t)(bb - nbr) * nblk;
        Btot = BtotC + (bb - nbr);
    }
    for (int i = t; i < nblk; i += 256) vals[i] = Hb[i];
    __syncthreads();
    int c0 = t * 2;
    int s = 0;
#pragma unroll
    for (int j = 0; j < 2; ++j)
        if (c0 + j < nblk) s += vals[c0 + j];
    part[t] = s;
    __syncthreads();
    for (int d = 1; d < 256; d <<= 1) {
        int add = (t >= d) ? part[t - d] : 0;
        __syncthreads();
        part[t] += add;
        __syncthreads();
    }
    int run = part[t] - s;
#pragma unroll
    for (int j = 0; j < 2; ++j) {
        int i = c0 + j;
        if (i < nblk) {
            int v = vals[i];
            Hb[i] = run;
            run += v;
        }
    }
    if (t == 255) *Btot = part[255];
}

// R21 scatter with inline base scan: every block scans BtotR/BtotC in LDS to
// build its cursors; block 0 publishes BbR/BbC (incl. [nb]=total). Then the
// dual scatter (plain stores, no global atomics).
__global__ __launch_bounds__(256) void k_scatter_dual(
    const int* __restrict__ row, const int* __restrict__ col,
    const int* __restrict__ Hr, const int* __restrict__ Hc,
    const int* __restrict__ BtotR, const int* __restrict__ BtotC,
    int* __restrict__ BbR, int* __restrict__ BbC,
    int* __restrict__ ebr, int* __restrict__ ebc,
    int e, int nblk, int nbr, int nbc) {
    __shared__ int vals[1024];
    __shared__ int part[256];
    __shared__ int curr[1024];
    __shared__ int curc[512];
    int t = threadIdx.x;
    int blk = blockIdx.x;
    // ---- scan BtotR -> curr = base + Hr[.][blk]; block 0 -> BbR
    for (int i = t; i < nbr; i += 256) vals[i] = BtotR[i];
    __syncthreads();
    {
        int c0 = t * 4, s = 0;
#pragma unroll
        for (int j = 0; j < 4; ++j)
            if (c0 + j < nbr) s += vals[c0 + j];
        part[t] = s;
        __syncthreads();
        for (int d = 1; d < 256; d <<= 1) {
            int add = (t >= d) ? part[t - d] : 0;
            __syncthreads();
            part[t] += add;
            __syncthreads();
        }
        int run = part[t] - s;
#pragma unroll
        for (int j = 0; j < 4; ++j) {
            int i = c0 + j;
            if (i < nbr) {
                int v = vals[i];
                curr[i] = run + Hr[(size_t)i * nblk + blk];
                if (blk == 0) BbR[i] = run;
                run += v;
            }
        }
        if (blk == 0 && t == 255) BbR[nbr] = part[255];
    }
    __syncthreads();
    // ---- scan BtotC -> curc; block 0 -> BbC
    for (int i = t; i < nbc; i += 256) vals[i] = BtotC[i];
    __syncthreads();
    {
        int c0 = t * 4, s = 0;
#pragma unroll
        for (int j = 0; j < 4; ++j)
            if (c0 + j < nbc) s += vals[c0 + j];
        part[t] = s;
        __syncthreads();
        for (int d = 1; d < 256; d <<= 1) {
            int add = (t >= d) ? part[t - d] : 0;
            __syncthreads();
            part[t] += add;
            __syncthreads();
        }
        int run = part[t] - s;
#pragma unroll
        for (int j = 0; j < 4; ++j) {
            int i = c0 + j;
            if (i < nbc) {
                int v = vals[i];
                curc[i] = run + Hc[(size_t)i * nblk + blk];
                if (blk == 0) BbC[i] = run;
                run += v;
            }
        }
        if (blk == 0 && t == 255) BbC[nbc] = part[255];
    }
    __syncthreads();
    // ---- dual scatter: ebr payload c<<7|r_low, ebc payload r<<8|c_low
    int base = blk * EC;
#pragma unroll
    for (int j = 0; j < EC / 256; ++j) {
        int i = base + t + j * 256;
        if (i < e) {
            int r = row[i], c = col[i];
            int pr = atomicAdd(&curr[r >> 7], 1);
            ebr[pr] = (c << 7) | (r & 127);
            int pc = atomicAdd(&curc[c >> 8], 1);
            ebc[pc] = (r << 8) | (c & 255);
        }
    }
}

// R22/R23 fused mid: blocks [0,ndenom) = R20 split-K denom slices (LDS acc,
// coalesced partials); blocks [ndenom, ndenom+nbr) = sort2 counting role
// (rowptr from per-row-bucket histogram). Independent workloads overlap.
__global__ __launch_bounds__(256) void k_mid(const int* __restrict__ ebc,
                                             const int* __restrict__ BbC,
                                             const int* __restrict__ ebr,
                                             const int* __restrict__ BbR,
                                             const float* __restrict__ s_src,
                                             const float* __restrict__ s_dst,
                                             float* __restrict__ part,
                                             int* __restrict__ rowptr,
                                             int n, int n4, int e, int ndenom) {
    __shared__ float acc[BSC * 4];
    __shared__ float sd[BSC * 4];
    __shared__ int cnt[BSR];
    __shared__ int pfx[BSR];
    int t = threadIdx.x;
    if (blockIdx.x < ndenom) {
        int bucket = blockIdx.x >> 2;
        int slice = blockIdx.x & 3;
        int cbase = bucket << 8;
        for (int i = t; i < BSC * 4; i += 256) {
            acc[i] = 0.0f;
            int c4 = cbase * 4 + i;
            sd[i] = (c4 < n4) ? s_dst[c4] : 0.0f;
        }
        __syncthreads();
        int start = BbC[bucket], end = BbC[bucket + 1];
        int len = end - start;
        int i0 = start + (int)(((long long)len * slice) >> 2);
        int i1 = start + (int)(((long long)len * (slice + 1)) >> 2);
        for (int i = i0 + t; i < i1; i += 256) {
            int p = ebc[i];
            int r = p >> 8, cl = p & 255;
            float4 ss = *(const float4*)(s_src + (size_t)r * 4);
            atomicAdd(&acc[cl * 4 + 0], __expf(LRELU(ss.x + sd[cl * 4 + 0])));
            atomicAdd(&acc[cl * 4 + 1], __expf(LRELU(ss.y + sd[cl * 4 + 1])));
            atomicAdd(&acc[cl * 4 + 2], __expf(LRELU(ss.z + sd[cl * 4 + 2])));
            atomicAdd(&acc[cl * 4 + 3], __expf(LRELU(ss.w + sd[cl * 4 + 3])));
        }
        __syncthreads();
        float* ps = part + (size_t)slice * n4;
        for (int i = t; i < BSC * 4; i += 256) {
            int c4 = cbase * 4 + i;
            if (c4 < n4) ps[c4] = acc[i];
        }
    } else {
        // ---- sort2 count role: per-row exclusive positions -> rowptr
        int b = blockIdx.x - ndenom;
        int rbase = b << 7;
        if (t < BSR) cnt[t] = 0;
        __syncthreads();
        int start = BbR[b], end = BbR[b + 1];
        for (int i = start + t; i < end; i += 256)
            atomicAdd(&cnt[ebr[i] & 127], 1);
        __syncthreads();
        if (t < BSR) pfx[t] = cnt[t];
        __syncthreads();
        for (int d = 1; d < BSR; d <<= 1) {
            int v = (t < BSR && t >= d) ? pfx[t - d] : 0;
            __syncthreads();
            if (t < BSR) pfx[t] += v;
            __syncthreads();
        }
        if (t < BSR) {
            int r = rbase + t;
            if (r < n) rowptr[r] = start + pfx[t] - cnt[t];
        }
        if (b == 0 && t == 0) rowptr[n] = e;
    }
}

// combine DS partials -> sdr[c] = {s_dst[c][0..3], 1/den[c][0..3]} (32B)
__global__ __launch_bounds__(256) void k_comb(const float* __restrict__ part,
                                              const float* __restrict__ s_dst,
                                              float* __restrict__ sdr, int n4) {
    int idx = blockIdx.x * 256 + threadIdx.x;
    if (idx >= n4) return;
    float s = part[idx] + part[(size_t)n4 + idx] + part[(size_t)2 * n4 + idx] +
              part[(size_t)3 * n4 + idx];
    int c = idx >> 2, h = idx & 3;
    sdr[(size_t)c * 8 + h] = s_dst[idx];
    sdr[(size_t)c * 8 + 4 + h] = 1.0f / (s + 1e-16f);
}

// R22 place pass: cursors rebuilt from rowptr (exact exclusive positions),
// then permute ebr -> row-sorted int2{c<<6, w}; one 32B sdr gather per edge.
__global__ __launch_bounds__(256) void k_place(const int* __restrict__ ebr,
                                               const int* __restrict__ BbR,
                                               const float* __restrict__ s_src,
                                               const float* __restrict__ sdr,
                                               const int* __restrict__ rowptr,
                                               int2* __restrict__ cwp,
                                               int n, int e) {
    __shared__ int cur[BSR];
    __shared__ float ssh[BSR * 4];
    int t = threadIdx.x;
    int b = blockIdx.x;
    int rbase = b << 7;
    if (t < BSR) cur[t] = rowptr[min(rbase + t, n)];
    for (int i = t; i < BSR * 4; i += 256) {
        int g = rbase * 4 + i;
        ssh[i] = (g < n * 4) ? s_src[g] : 0.0f;
    }
    __syncthreads();
    int start = BbR[b], end = BbR[b + 1];
    for (int i = start + t; i < end; i += 256) {
        int p = ebr[i];
        int rl = p & 127, c = p >> 7;
        float4 sd = *(const float4*)(sdr + (size_t)c * 8);
        float4 rd = *(const float4*)(sdr + (size_t)c * 8 + 4);
        float wv = __expf(LRELU(ssh[rl * 4 + 0] + sd.x)) * rd.x +
                   __expf(LRELU(ssh[rl * 4 + 1] + sd.y)) * rd.y +
                   __expf(LRELU(ssh[rl * 4 + 2] + sd.z)) * rd.z +
                   __expf(LRELU(ssh[rl * 4 + 3] + sd.w)) * rd.w;
        int pos = atomicAdd(&cur[rl], 1);
        // c pre-shifted to element offset (c*64) for k_aggr's 32-bit addressing
        cwp[pos] = make_int2(c << 6, __float_as_int(0.25f * wv));
    }
}

// R15 wave-per-row CSR gather-reduce: 8 groups x 8 lanes, each group gathers a
// different edge's 128B row as uint4 (16B/lane = 8 bf16). SLOTS=4 unrolled ->
// up to 32 edges in flight; slots gated by k<nk (wave-uniform skip).
__global__ __launch_bounds__(256) void k_aggr(const int* __restrict__ rowptr,
                                              const int2* __restrict__ cwp,
                                              const unsigned short* __restrict__ xt16,
                                              float* __restrict__ out, int n, int e) {
    int r = blockIdx.x * 4 + (threadIdx.x >> 6);
    if (r >= n) return;
    int lane = threadIdx.x & 63;
    int g = lane >> 3;          // edge group 0..7
    unsigned le = (lane & 7) << 3;  // covers cols [le, le+8)
    int start = rowptr[r], end = rowptr[r + 1];
    float acc[8];
#pragma unroll
    for (int j = 0; j < 8; ++j) acc[j] = 0.0f;
    for (int base = start; base < end; base += SLOTS * 8) {
        int m = end - base;
        if (m > SLOTS * 8) m = SLOTS * 8;
        int nk = (m + 7) >> 3;  // slots needed (wave-uniform)
        uint4 u[SLOTS];
        float wv[SLOTS];
#pragma unroll
        for (int k = 0; k < SLOTS; ++k) {
            if (k < nk) {
                int idx = base + k * 8 + g;
                int idc = idx < e ? idx : e - 1;  // stay in-buffer
                int2 cw = cwp[idc];              // 8B meta, broadcast in group
                wv[k] = (idx < end) ? __int_as_float(cw.y) : 0.0f;
                u[k] = *(const uint4*)(xt16 + ((unsigned)cw.x + le));
            }
        }
#pragma unroll
        for (int k = 0; k < SLOTS; ++k) {
            if (k < nk) {
                acc[0] = fmaf(wv[k], bflo(u[k].x), acc[0]);
                acc[1] = fmaf(wv[k], bfhi(u[k].x), acc[1]);
                acc[2] = fmaf(wv[k], bflo(u[k].y), acc[2]);
                acc[3] = fmaf(wv[k], bfhi(u[k].y), acc[3]);
                acc[4] = fmaf(wv[k], bflo(u[k].z), acc[4]);
                acc[5] = fmaf(wv[k], bfhi(u[k].z), acc[5]);
                acc[6] = fmaf(wv[k], bflo(u[k].w), acc[6]);
                acc[7] = fmaf(wv[k], bfhi(u[k].w), acc[7]);
            }
        }
    }
#pragma unroll
    for (int off = 8; off <= 32; off <<= 1) {
#pragma unroll
        for (int j = 0; j < 8; ++j) acc[j] += __shfl_xor(acc[j], off, 64);
    }
    if (lane < 8) {
        float4 a0 = {acc[0], acc[1], acc[2], acc[3]};
        float4 a1 = {acc[4], acc[5], acc[6], acc[7]};
        *(float4*)(out + (size_t)r * 64 + le) = a0;
        *(float4*)(out + (size_t)r * 64 + le + 4) = a1;
    }
}

extern "C" void kernel_launch(void* const* d_in, const int* in_sizes, int n_in,
                              void* d_out, int out_size, void* d_ws, size_t ws_size,
                              hipStream_t stream) {
    const float* x = (const float*)d_in[0];
    const int* ei = (const int*)d_in[1];
    // d_in[2] = edge_weight: unused by the reference
    const float* W = (const float*)d_in[3];
    const float* a = (const float*)d_in[4];
    int n = in_sizes[0] / 64;
    int e = in_sizes[1] / 2;
    const int* row = ei;
    const int* col = ei + e;
    float* out = (float*)d_out;

    int nblk = (e + EC - 1) / EC;       // 391 (<=512 for k_scanH2)
    int nbr = (n + BSR - 1) / BSR;      // 782 (<=1024 for scatter scan)
    int nbc = (n + BSC - 1) / BSC;      // 391 (<=512)
    int nbn = (n + 63) / 64;            // 1563 node blocks in k_front
    int n4 = n * 4;
    int ndenom = nbc * DS;              // 1564 denom slices in k_mid

    size_t o = 0;
    auto take = [&](size_t cnt) {
        size_t p = o;
        o += (cnt + 3) & ~(size_t)3;
        return p;
    };
    int* wsi = (int*)d_ws;
    unsigned short* xt16 = (unsigned short*)(wsi + take((size_t)n * 32));  // n*64 bf16
    float* s_src = (float*)(wsi + take((size_t)n * 4));
    float* s_dst = (float*)(wsi + take((size_t)n * 4));
    float* sdr = (float*)(wsi + take((size_t)n * 8));  // merged {s_dst, 1/den}
    float* part = (float*)(wsi + take((size_t)n * 4 * DS));  // denom partials
    int* Hr = wsi + take((size_t)nbr * nblk);
    int* Hc = wsi + take((size_t)nbc * nblk);
    int* BtotR = wsi + take(nbr);
    int* BbR = wsi + take(nbr + 1);
    int* BtotC = wsi + take(nbc);
    int* BbC = wsi + take(nbc + 1);
    int* ebr = wsi + take(e);
    int* cwbuf = wsi + take((size_t)2 * e);  // first e ints double as ebc
    int* ebc = cwbuf;            // dead after k_mid; k_place overwrites as int2
    int2* cwp = (int2*)cwbuf;
    int* rowptr = wsi + take(n + 1);

    // Fold 4-step (q,p) <- (q+0.25p, p-0.25q): xt = aq*x + bq*(x@W^T)
    float aq = 1.f, bq = 0.f, ap = 0.f, bp = 1.f;
    for (int i = 0; i < 4; ++i) {
        float naq = aq + 0.25f * ap, nbq = bq + 0.25f * bp;
        float nap = ap - 0.25f * aq, nbp = bp - 0.25f * bq;
        aq = naq; bq = nbq; ap = nap; bp = nbp;
    }

    k_front<<<nbn + nblk, 256, 0, stream>>>(x, W, a, row, col, xt16, s_src,
                                            s_dst, Hr, Hc, n, e, nbn, nblk,
                                            nbr, nbc, aq, bq);
    k_scanH2<<<nbr + nbc, 256, 0, stream>>>(Hr, Hc, BtotR, BtotC, nblk, nbr);
    k_scatter_dual<<<nblk, 256, 0, stream>>>(row, col, Hr, Hc, BtotR, BtotC,
                                             BbR, BbC, ebr, ebc, e, nblk,
                                             nbr, nbc);
    k_mid<<<ndenom + nbr, 256, 0, stream>>>(ebc, BbC, ebr, BbR, s_src, s_dst,
                                            part, rowptr, n, n4, e, ndenom);
    k_comb<<<(n4 + 255) / 256, 256, 0, stream>>>(part, s_dst, sdr, n4);
    k_place<<<nbr, 256, 0, stream>>>(ebr, BbR, s_src, sdr, rowptr, cwp, n, e);
    k_aggr<<<(n + 3) / 4, 256, 0, stream>>>(rowptr, cwp, xt16, out, n, e);
}